// Round 7
// baseline (1970.287 us; speedup 1.0000x reference)
//
#include <hip/hip_runtime.h>

#define C 128

typedef __attribute__((ext_vector_type(8))) short short8v;
typedef __attribute__((ext_vector_type(4))) float float4v;

__device__ __forceinline__ ushort f2bf(float f) {
  union { float f; uint u; } v; v.f = f;
  uint u = v.u;
  return (ushort)((u + 0x7FFF + ((u >> 16) & 1)) >> 16);  // RNE
}
__device__ __forceinline__ float bf2f(ushort s) {
  union { uint u; float f; } v; v.u = ((uint)s) << 16; return v.f;
}
// truncation hi/lo split: hi+lo == f to 2^-16 rel (pair-exact enough);
// ~3 VALU ops vs ~11 for the RNE version. Only valid when hi is never
// used without lo.
__device__ __forceinline__ void split2(float f, short& hi, short& lo) {
  union { float f; uint u; } v; v.f = f;
  uint uh = v.u & 0xFFFF0000u;
  hi = (short)(uh >> 16);
  union { uint u; float f; } w; w.u = uh;
  union { float f; uint u; } x; x.f = f - w.f;
  lo = (short)(x.u >> 16);
}

// LDS swizzles: row-stride 128 shorts (16 chunks of 8) / 64 shorts (8 chunks)
__device__ __forceinline__ short* swz(short* base, int row, int chunk) {
  return base + row * 128 + ((chunk ^ (row & 15)) << 3);
}
__device__ __forceinline__ short* swz8(short* base, int row, int chunk) {
  return base + row * 64 + ((chunk ^ (row & 7)) << 3);
}

// ---------------- degree count ------------------------------------------
__global__ void k_degree(const int* __restrict__ col, int* __restrict__ cnt, int E) {
  int e = blockIdx.x * blockDim.x + threadIdx.x;
  if (e < E) atomicAdd(&cnt[col[e]], 1);
}

// ---------------- single-block scan: deg -> dis, indptr, cursor --------
__global__ void k_scan(const int* __restrict__ cnt, float* __restrict__ dis,
                       int* __restrict__ indptr, int* __restrict__ cursor, int N) {
  __shared__ int sb[1024];
  int t = threadIdx.x;
  int chunk = (N + 1023) >> 10;
  int lo = t * chunk, hi = min(lo + chunk, N);
  int sum = 0;
  for (int i = lo; i < hi; ++i) sum += cnt[i];
  sb[t] = sum;
  __syncthreads();
  for (int off = 1; off < 1024; off <<= 1) {
    int v = (t >= off) ? sb[t - off] : 0;
    __syncthreads();
    sb[t] += v;
    __syncthreads();
  }
  int run = sb[t] - sum;
  for (int i = lo; i < hi; ++i) {
    indptr[i] = run; cursor[i] = run;
    dis[i] = rsqrtf((float)(cnt[i] + 1));
    run += cnt[i];
  }
  if (lo < N && hi == N) indptr[N] = run;
}

// ---------------- CSR fill: dst-sorted meta + inverse permutation -------
__global__ void k_csrfill(const int* __restrict__ row, const int* __restrict__ col,
                          const float* __restrict__ dis, int* __restrict__ cursor,
                          int2* __restrict__ emeta, int2* __restrict__ epair,
                          int* __restrict__ inv, int E) {
  int e = blockIdx.x * blockDim.x + threadIdx.x;
  if (e >= E) return;
  int r = row[e], c = col[e];
  int pos = atomicAdd(&cursor[c], 1);
  float nrm = dis[r] * dis[c];
  emeta[pos] = make_int2(r, __float_as_int(nrm));
  epair[pos] = make_int2(r, c);
  inv[e] = pos;           // coalesced by e; k_perm gathers tmp[inv[e]]
}

// ---------------- W1 -> bf16 fragment-major table -----------------------
// Wf[((kk*8 + j)*64 + lane)*8 + e] = bf16(W1[k][n]), n = j*16+(lane&15),
// k = (kk*4+(lane>>4))*8 + e.  One wave's b-fragment load for (kk,j) is a
// contiguous, coalesced 1KB global_load_dwordx4 (vs 64-line gather from
// row-major W1t) — lets k_edge skip W LDS staging entirely.
__global__ void k_prepwf(const float* __restrict__ W1, ushort* __restrict__ Wf) {
  int idx = blockIdx.x * 256 + threadIdx.x;  // 16384
  int e = idx & 7, lane = (idx >> 3) & 63, j = (idx >> 9) & 7, kk = idx >> 12;
  int n = j * 16 + (lane & 15);
  int k = (kk * 4 + (lane >> 4)) * 8 + e;
  Wf[idx] = f2bf(W1[k * C + n]);
}

// ---------------- conv/fc0 W^T -> bf16 hi/lo (10 matrices) --------------
__global__ void k_prepw2(const float* __restrict__ convs_W,
                         const float* __restrict__ fc0_W,
                         ushort* __restrict__ Wth, ushort* __restrict__ Wtl) {
  int g = blockIdx.x * 256 + threadIdx.x;  // [0, 10*16384)
  int mat = g >> 14, idx = g & 16383;
  int n = idx >> 7, k = idx & 127;
  const float* src = (mat < 8) ? convs_W + ((size_t)mat << 14)
                               : fc0_W + ((size_t)(mat - 8) << 14);
  float v = src[k * C + n];
  ushort h = f2bf(v);
  Wth[g] = h;
  Wtl[g] = f2bf(v - bf2f(h));
}

// ---------------- aggregation: agg[v] = sum norm*h[src] + dis^2*h[v] ----
__global__ __launch_bounds__(256)
void k_agg(const float* __restrict__ h, const int* __restrict__ indptr,
           const int2* __restrict__ emeta, const float* __restrict__ dis,
           float* __restrict__ agg, int N) {
  int w = (blockIdx.x * 256 + threadIdx.x) >> 6;
  int lane = threadIdx.x & 63;
  if (w >= N) return;
  int s = indptr[w], e = indptr[w + 1];
  float ax = 0.f, ay = 0.f;
  int i = s;
  for (; i + 8 <= e; i += 8) {  // 8 independent row loads in flight
    int2 m[8];
#pragma unroll
    for (int u = 0; u < 8; ++u) m[u] = emeta[i + u];
    float2 hv[8];
#pragma unroll
    for (int u = 0; u < 8; ++u)
      hv[u] = *(const float2*)(h + (size_t)m[u].x * C + lane * 2);
#pragma unroll
    for (int u = 0; u < 8; ++u) {
      float nn = __int_as_float(m[u].y);
      ax += nn * hv[u].x; ay += nn * hv[u].y;
    }
  }
  for (; i < e; ++i) {
    int2 m0 = emeta[i];
    float2 h0 = *(const float2*)(h + (size_t)m0.x * C + lane * 2);
    float n0 = __int_as_float(m0.y);
    ax += n0 * h0.x; ay += n0 * h0.y;
  }
  float dv = dis[w];
  float2 hs = *(const float2*)(h + (size_t)w * C + lane * 2);
  ax += dv * dv * hs.x; ay += dv * dv * hs.y;
  float2 o; o.x = ax; o.y = ay;
  *(float2*)(agg + (size_t)w * C + lane * 2) = o;
}

// ---------------- MFMA GEMM: out[M,128] = op(A[M,128] @ W) --------------
__global__ __launch_bounds__(256, 2)
void k_gemm_mfma(const float* __restrict__ A, const ushort* __restrict__ Wth,
                 const ushort* __restrict__ Wtl, const float* __restrict__ bias,
                 const float* __restrict__ skip, float* __restrict__ out,
                 int M, int relu) {
  __shared__ __align__(16) short Ah[64 * 128];
  __shared__ __align__(16) short Al[64 * 128];
  __shared__ __align__(16) short Wh[128 * 64];
  __shared__ __align__(16) short Wl[128 * 64];
  int t = threadIdx.x;
  int r0 = blockIdx.x * 64;
  {
    int rl = t >> 2, p = t & 3;
    int r = r0 + rl;
    const float* Ar = A + (size_t)r * C + p * 32;
#pragma unroll
    for (int i = 0; i < 4; ++i) {
      float v[8];
      if (r < M) {
        float4 a0 = *(const float4*)(Ar + 8 * i);
        float4 a1 = *(const float4*)(Ar + 8 * i + 4);
        v[0] = a0.x; v[1] = a0.y; v[2] = a0.z; v[3] = a0.w;
        v[4] = a1.x; v[5] = a1.y; v[6] = a1.z; v[7] = a1.w;
      } else {
#pragma unroll
        for (int j = 0; j < 8; ++j) v[j] = 0.f;
      }
      short8v hi, lo;
#pragma unroll
      for (int j = 0; j < 8; ++j) { short h_, l_; split2(v[j], h_, l_); hi[j] = h_; lo[j] = l_; }
      *(short8v*)swz(Ah, rl, p * 4 + i) = hi;
      *(short8v*)swz(Al, rl, p * 4 + i) = lo;
    }
  }
  int w = t >> 6, lane = t & 63;
  int m0 = w * 16;
  int lm = lane & 15, lq = lane >> 4;
  float4v acc[8];
#pragma unroll
  for (int j = 0; j < 8; ++j) acc[j] = (float4v){0.f, 0.f, 0.f, 0.f};

  for (int half = 0; half < 2; ++half) {
    __syncthreads();
    {
#pragma unroll
      for (int i = 0; i < 4; ++i) {
        int g = i * 256 + t;
        int n = g >> 3, kc = g & 7;
        size_t off = (size_t)n * 128 + half * 64 + kc * 8;
        *(short8v*)swz8(Wh, n, kc) = *(const short8v*)(Wth + off);
        *(short8v*)swz8(Wl, n, kc) = *(const short8v*)(Wtl + off);
      }
    }
    __syncthreads();
#pragma unroll
    for (int kk = 0; kk < 2; ++kk) {
      int ach = (half * 2 + kk) * 4 + lq;
      int wch = kk * 4 + lq;
      short8v ah = *(const short8v*)swz(Ah, m0 + lm, ach);
      short8v al = *(const short8v*)swz(Al, m0 + lm, ach);
#pragma unroll
      for (int j = 0; j < 8; ++j) {
        short8v bh = *(const short8v*)swz8(Wh, j * 16 + lm, wch);
        short8v bl = *(const short8v*)swz8(Wl, j * 16 + lm, wch);
        acc[j] = __builtin_amdgcn_mfma_f32_16x16x32_bf16(ah, bh, acc[j], 0, 0, 0);
        acc[j] = __builtin_amdgcn_mfma_f32_16x16x32_bf16(al, bh, acc[j], 0, 0, 0);
        acc[j] = __builtin_amdgcn_mfma_f32_16x16x32_bf16(ah, bl, acc[j], 0, 0, 0);
      }
    }
  }
#pragma unroll
  for (int j = 0; j < 8; ++j) {
    int n = j * 16 + lm;
    float bv = bias ? bias[n] : 0.f;
#pragma unroll
    for (int r = 0; r < 4; ++r) {
      int m = r0 + m0 + lq * 4 + r;
      if (m >= M) continue;
      float v = acc[j][r] + bv;
      if (skip) v += skip[(size_t)m * C + n];
      if (relu) v = fmaxf(v, 0.f);
      out[(size_t)m * C + n] = v;
    }
  }
}

// ---------------- fused edge MLP (CSR order, W from global) --------------
// LDS = EtH+EtL = 32KB only -> 4 blocks/CU for gather-latency hiding.
// B-fragments read from the fragment-major Wf table (coalesced, L2-hot).
__global__ __launch_bounds__(256, 4)
void k_edge(const float* __restrict__ P, const float* __restrict__ Q,
            const int2* __restrict__ epair, const ushort* __restrict__ Wf,
            const float* __restrict__ b1, const float* __restrict__ w2,
            const float* __restrict__ b2, float* __restrict__ tmpout, int E) {
  __shared__ __align__(16) short EtH[64 * 128];
  __shared__ __align__(16) short EtL[64 * 128];
  int t = threadIdx.x;
  int p0 = blockIdx.x * 64;
  {
    int el = t >> 2, p4 = t & 3;
    int p = p0 + el;
    if (p >= E) p = E - 1;
    int2 rc = epair[p];
    const float* Pp = P + (size_t)rc.x * C + p4 * 32;
    const float* Qp = Q + (size_t)rc.y * C + p4 * 32;
#pragma unroll
    for (int i = 0; i < 4; ++i) {
      float4 a0 = *(const float4*)(Pp + 8 * i);
      float4 a1 = *(const float4*)(Pp + 8 * i + 4);
      float4 b0 = *(const float4*)(Qp + 8 * i);
      float4 b1v4 = *(const float4*)(Qp + 8 * i + 4);
      float v[8] = {a0.x + b0.x, a0.y + b0.y, a0.z + b0.z, a0.w + b0.w,
                    a1.x + b1v4.x, a1.y + b1v4.y, a1.z + b1v4.z, a1.w + b1v4.w};
      short8v hi, lo;
#pragma unroll
      for (int j = 0; j < 8; ++j) {
        short h_, l_;
        split2(fmaxf(v[j], 0.f), h_, l_);
        hi[j] = h_; lo[j] = l_;
      }
      *(short8v*)swz(EtH, el, p4 * 4 + i) = hi;
      *(short8v*)swz(EtL, el, p4 * 4 + i) = lo;
    }
  }
  __syncthreads();

  int w = t >> 6, lane = t & 63;
  int m0 = w * 16;
  int lm = lane & 15, lq = lane >> 4;
  float4v acc[8];
#pragma unroll
  for (int j = 0; j < 8; ++j) acc[j] = (float4v){0.f, 0.f, 0.f, 0.f};

#pragma unroll
  for (int kk = 0; kk < 4; ++kk) {
    int ch = kk * 4 + lq;
    short8v ah = *(const short8v*)swz(EtH, m0 + lm, ch);
    short8v al = *(const short8v*)swz(EtL, m0 + lm, ch);
#pragma unroll
    for (int j = 0; j < 8; ++j) {
      short8v b = *(const short8v*)(Wf + (((kk * 8 + j) * 64 + lane) << 3));
      acc[j] = __builtin_amdgcn_mfma_f32_16x16x32_bf16(ah, b, acc[j], 0, 0, 0);
      acc[j] = __builtin_amdgcn_mfma_f32_16x16x32_bf16(al, b, acc[j], 0, 0, 0);
    }
  }

  float partv[4] = {0.f, 0.f, 0.f, 0.f};
#pragma unroll
  for (int j = 0; j < 8; ++j) {
    int n = j * 16 + lm;
    float b1v = b1[n], w2v = w2[n];
#pragma unroll
    for (int r = 0; r < 4; ++r) {
      float e2 = fmaxf(acc[j][r] + b1v, 0.f);
      partv[r] = fmaf(e2, w2v, partv[r]);
    }
  }
#pragma unroll
  for (int off = 1; off < 16; off <<= 1) {
#pragma unroll
    for (int r = 0; r < 4; ++r) partv[r] += __shfl_xor(partv[r], off, 64);
  }
  if (lm == 0) {
    float bb = b2[0];
#pragma unroll
    for (int r = 0; r < 4; ++r) {
      int p = p0 + m0 + lq * 4 + r;
      if (p < E) tmpout[p] = partv[r] + bb;  // coalesced (CSR order)
    }
  }
}

// ---------------- permute: out[e] = tmp[inv[e]] (coalesced write) --------
__global__ void k_perm(const float* __restrict__ tmp, const int* __restrict__ inv,
                       float* __restrict__ out, int E) {
  int e = blockIdx.x * 256 + threadIdx.x;
  if (e < E) out[e] = tmp[inv[e]];  // gather from L2-resident 6.4MB
}

// ---------------- host ---------------------------------------------------
extern "C" void kernel_launch(void* const* d_in, const int* in_sizes, int n_in,
                              void* d_out, int out_size, void* d_ws, size_t ws_size,
                              hipStream_t stream) {
  const float* x       = (const float*)d_in[0];
  const int*   ei      = (const int*)d_in[1];
  const float* convs_W = (const float*)d_in[2];
  const float* convs_b = (const float*)d_in[3];
  const float* fc0_W   = (const float*)d_in[4];
  const float* fc0_b   = (const float*)d_in[5];
  const float* fc1_W   = (const float*)d_in[6];
  const float* fc1_b   = (const float*)d_in[7];
  const float* fc2_W   = (const float*)d_in[8];
  const float* fc2_b   = (const float*)d_in[9];
  float* out = (float*)d_out;

  const int N = in_sizes[0] / C;        // 50000
  const int E = in_sizes[1] / 2;        // 1600000
  const int L = in_sizes[2] / (C * C);  // 8
  const int* row = ei;
  const int* col = ei + E;

  char* wp = (char*)d_ws;
  auto carve = [&](size_t bytes) {
    char* p = wp; wp += (bytes + 255) & ~(size_t)255; return p;
  };
  int*    cnt    = (int*)carve((size_t)N * 4);
  int*    indptr = (int*)carve((size_t)(N + 1) * 4);
  int*    cursor = (int*)carve((size_t)N * 4);
  float*  dis    = (float*)carve((size_t)N * 4);
  int2*   emeta  = (int2*)carve((size_t)E * 8);
  int2*   epair  = (int2*)carve((size_t)E * 8);
  int*    inv    = (int*)carve((size_t)E * 4);
  float*  tmpout = (float*)carve((size_t)E * 4);
  ushort* Wf     = (ushort*)carve((size_t)C * C * 2);
  ushort* Wth    = (ushort*)carve((size_t)10 * C * C * 2);
  ushort* Wtl    = (ushort*)carve((size_t)10 * C * C * 2);
  float*  big0   = (float*)carve((size_t)N * C * 4);
  float*  big1   = (float*)carve((size_t)N * C * 4);
  float*  big2   = (float*)carve((size_t)N * C * 4);

  hipMemsetAsync(cnt, 0, (size_t)N * 4, stream);
  k_degree<<<(E + 255) / 256, 256, 0, stream>>>(col, cnt, E);
  k_scan<<<1, 1024, 0, stream>>>(cnt, dis, indptr, cursor, N);
  k_csrfill<<<(E + 255) / 256, 256, 0, stream>>>(row, col, dis, cursor,
                                                 emeta, epair, inv, E);
  k_prepwf<<<C * C / 256, 256, 0, stream>>>(fc1_W, Wf);
  k_prepw2<<<10 * C * C / 256, 256, 0, stream>>>(convs_W, fc0_W, Wth, Wtl);

  int aggBlocks  = (N * 64 + 255) / 256;
  int gemmBlocks = (N + 63) / 64;
  const int MSZ = C * C;

  // layer 0 (no skip)
  k_agg<<<aggBlocks, 256, 0, stream>>>(x, indptr, emeta, dis, big1, N);
  k_gemm_mfma<<<gemmBlocks, 256, 0, stream>>>(big1, Wth, Wtl, convs_b, nullptr,
                                              big0, N, 1);
  float* hcur = big0; float* fA = big1; float* fB = big2;
  for (int l = 1; l < L; ++l) {
    k_agg<<<aggBlocks, 256, 0, stream>>>(hcur, indptr, emeta, dis, fA, N);
    k_gemm_mfma<<<gemmBlocks, 256, 0, stream>>>(fA, Wth + (size_t)l * MSZ,
                                                Wtl + (size_t)l * MSZ,
                                                convs_b + (size_t)l * C, hcur,
                                                fB, N, 1);
    float* tmp = hcur; hcur = fB; fB = tmp;
  }
  // edge MLP: P = h@fc0_W[:128], Q = h@fc0_W[128:] + b0
  float* Pm = fA; float* Qm = fB;
  k_gemm_mfma<<<gemmBlocks, 256, 0, stream>>>(hcur, Wth + (size_t)8 * MSZ,
                                              Wtl + (size_t)8 * MSZ, nullptr,
                                              nullptr, Pm, N, 0);
  k_gemm_mfma<<<gemmBlocks, 256, 0, stream>>>(hcur, Wth + (size_t)9 * MSZ,
                                              Wtl + (size_t)9 * MSZ, fc0_b,
                                              nullptr, Qm, N, 0);
  k_edge<<<(E + 63) / 64, 256, 0, stream>>>(Pm, Qm, epair, Wf, fc1_b,
                                            fc2_W, fc2_b, tmpout, E);
  k_perm<<<(E + 255) / 256, 256, 0, stream>>>(tmpout, inv, out, E);
}

// Round 8
// 1348.777 us; speedup vs baseline: 1.4608x; 1.4608x over previous
//
#include <hip/hip_runtime.h>

#define C 128

typedef __attribute__((ext_vector_type(8))) short short8v;
typedef __attribute__((ext_vector_type(4))) float float4v;
typedef _Float16 half8v __attribute__((ext_vector_type(8)));
typedef _Float16 half4v __attribute__((ext_vector_type(4)));
typedef _Float16 half2v __attribute__((ext_vector_type(2)));

__device__ __forceinline__ ushort f2bf(float f) {
  union { float f; uint u; } v; v.f = f;
  uint u = v.u;
  return (ushort)((u + 0x7FFF + ((u >> 16) & 1)) >> 16);  // RNE
}
__device__ __forceinline__ float bf2f(ushort s) {
  union { uint u; float f; } v; v.u = ((uint)s) << 16; return v.f;
}
// truncation hi/lo split: pair-exact to 2^-16 rel; hi never used without lo
__device__ __forceinline__ void split2(float f, short& hi, short& lo) {
  union { float f; uint u; } v; v.f = f;
  uint uh = v.u & 0xFFFF0000u;
  hi = (short)(uh >> 16);
  union { uint u; float f; } w; w.u = uh;
  union { float f; uint u; } x; x.f = f - w.f;
  lo = (short)(x.u >> 16);
}

// LDS swizzles (units = elements; row stride 128 elems, 16 chunks of 8 / 8 chunks)
__device__ __forceinline__ short* swz(short* base, int row, int chunk) {
  return base + row * 128 + ((chunk ^ (row & 15)) << 3);
}
__device__ __forceinline__ short* swz8(short* base, int row, int chunk) {
  return base + row * 64 + ((chunk ^ (row & 7)) << 3);
}
__device__ __forceinline__ _Float16* swzh(_Float16* base, int row, int chunk) {
  return base + row * 128 + ((chunk ^ (row & 15)) << 3);
}

// ---------------- degree count ------------------------------------------
__global__ void k_degree(const int* __restrict__ col, int* __restrict__ cnt, int E) {
  int e = blockIdx.x * blockDim.x + threadIdx.x;
  if (e < E) atomicAdd(&cnt[col[e]], 1);
}

// ---------------- single-block scan -------------------------------------
__global__ void k_scan(const int* __restrict__ cnt, float* __restrict__ dis,
                       int* __restrict__ indptr, int* __restrict__ cursor, int N) {
  __shared__ int sb[1024];
  int t = threadIdx.x;
  int chunk = (N + 1023) >> 10;
  int lo = t * chunk, hi = min(lo + chunk, N);
  int sum = 0;
  for (int i = lo; i < hi; ++i) sum += cnt[i];
  sb[t] = sum;
  __syncthreads();
  for (int off = 1; off < 1024; off <<= 1) {
    int v = (t >= off) ? sb[t - off] : 0;
    __syncthreads();
    sb[t] += v;
    __syncthreads();
  }
  int run = sb[t] - sum;
  for (int i = lo; i < hi; ++i) {
    indptr[i] = run; cursor[i] = run;
    dis[i] = rsqrtf((float)(cnt[i] + 1));
    run += cnt[i];
  }
  if (lo < N && hi == N) indptr[N] = run;
}

// ---------------- CSR fill ----------------------------------------------
__global__ void k_csrfill(const int* __restrict__ row, const int* __restrict__ col,
                          const float* __restrict__ dis, int* __restrict__ cursor,
                          int2* __restrict__ emeta, int2* __restrict__ epair,
                          int* __restrict__ inv, int E) {
  int e = blockIdx.x * blockDim.x + threadIdx.x;
  if (e >= E) return;
  int r = row[e], c = col[e];
  int pos = atomicAdd(&cursor[c], 1);
  float nrm = dis[r] * dis[c];
  emeta[pos] = make_int2(r, __float_as_int(nrm));
  epair[pos] = make_int2(r, c);
  inv[e] = pos;
}

// ---------------- x fp32 -> fp16 ----------------------------------------
__global__ void k_cvt(const float* __restrict__ x, _Float16* __restrict__ xh, int n4) {
  int i = blockIdx.x * 256 + threadIdx.x;
  if (i >= n4) return;
  float4 v = ((const float4*)x)[i];
  half4v o = {(_Float16)v.x, (_Float16)v.y, (_Float16)v.z, (_Float16)v.w};
  *(half4v*)(xh + i * 4) = o;
}

// ---------------- W1 -> fp16 fragment-major table -----------------------
// Wf[((kk*8+j)*64+lane)*8+e] = fp16(W1[k][n]), n=j*16+(lane&15),
// k=kk*32+(lane>>4)*8+e. Wave b-load for (kk,j) = coalesced 1KB.
__global__ void k_prepwf(const float* __restrict__ W1, _Float16* __restrict__ Wf) {
  int idx = blockIdx.x * 256 + threadIdx.x;  // 16384
  int e = idx & 7, lane = (idx >> 3) & 63, j = (idx >> 9) & 7, kk = idx >> 12;
  int n = j * 16 + (lane & 15);
  int k = (kk * 4 + (lane >> 4)) * 8 + e;
  Wf[idx] = (_Float16)W1[k * C + n];
}

// ---------------- conv/fc0 W^T -> bf16 hi/lo (10 matrices) --------------
__global__ void k_prepw2(const float* __restrict__ convs_W,
                         const float* __restrict__ fc0_W,
                         ushort* __restrict__ Wth, ushort* __restrict__ Wtl) {
  int g = blockIdx.x * 256 + threadIdx.x;  // [0, 10*16384)
  int mat = g >> 14, idx = g & 16383;
  int n = idx >> 7, k = idx & 127;
  const float* src = (mat < 8) ? convs_W + ((size_t)mat << 14)
                               : fc0_W + ((size_t)(mat - 8) << 14);
  float v = src[k * C + n];
  ushort h = f2bf(v);
  Wth[g] = h;
  Wtl[g] = f2bf(v - bf2f(h));
}

// ---------------- aggregation (fp16 h): agg fp32 ------------------------
__global__ __launch_bounds__(256)
void k_agg(const _Float16* __restrict__ h, const int* __restrict__ indptr,
           const int2* __restrict__ emeta, const float* __restrict__ dis,
           float* __restrict__ agg, int N) {
  int w = (blockIdx.x * 256 + threadIdx.x) >> 6;
  int lane = threadIdx.x & 63;
  if (w >= N) return;
  int s = indptr[w], e = indptr[w + 1];
  float ax = 0.f, ay = 0.f;
  int i = s;
  for (; i + 8 <= e; i += 8) {  // 8 independent row loads in flight
    int2 m[8];
#pragma unroll
    for (int u = 0; u < 8; ++u) m[u] = emeta[i + u];
    half2v hv[8];
#pragma unroll
    for (int u = 0; u < 8; ++u)
      hv[u] = *(const half2v*)(h + (size_t)m[u].x * C + lane * 2);
#pragma unroll
    for (int u = 0; u < 8; ++u) {
      float nn = __int_as_float(m[u].y);
      ax += nn * (float)hv[u][0]; ay += nn * (float)hv[u][1];
    }
  }
  for (; i < e; ++i) {
    int2 m0 = emeta[i];
    half2v h0 = *(const half2v*)(h + (size_t)m0.x * C + lane * 2);
    float n0 = __int_as_float(m0.y);
    ax += n0 * (float)h0[0]; ay += n0 * (float)h0[1];
  }
  float dv = dis[w];
  half2v hs = *(const half2v*)(h + (size_t)w * C + lane * 2);
  ax += dv * dv * (float)hs[0]; ay += dv * dv * (float)hs[1];
  float2 o; o.x = ax; o.y = ay;
  *(float2*)(agg + (size_t)w * C + lane * 2) = o;
}

// ---------------- MFMA GEMM: out_fp16[M,128] = op(A @ W) ----------------
// A fp32 (agg) or fp16 (h) -> bf16 hi/lo LDS; W^T bf16 hi/lo, 3-term
// product = fp32-equivalent. Output fp16.
__global__ __launch_bounds__(256, 2)
void k_gemm_mfma(const void* __restrict__ Av, int a_f16,
                 const ushort* __restrict__ Wth, const ushort* __restrict__ Wtl,
                 const float* __restrict__ bias, const _Float16* __restrict__ skip,
                 _Float16* __restrict__ out, int M, int relu) {
  __shared__ __align__(16) short Ah[64 * 128];
  __shared__ __align__(16) short Al[64 * 128];
  __shared__ __align__(16) short Wh[128 * 64];
  __shared__ __align__(16) short Wl[128 * 64];
  int t = threadIdx.x;
  int r0 = blockIdx.x * 64;
  {
    int rl = t >> 2, p = t & 3;
    int r = r0 + rl;
#pragma unroll
    for (int i = 0; i < 4; ++i) {
      float v[8];
      if (r < M) {
        if (a_f16) {
          const _Float16* Ar = (const _Float16*)Av + (size_t)r * C + p * 32;
          half8v a = *(const half8v*)(Ar + 8 * i);
#pragma unroll
          for (int j = 0; j < 8; ++j) v[j] = (float)a[j];
        } else {
          const float* Ar = (const float*)Av + (size_t)r * C + p * 32;
          float4 a0 = *(const float4*)(Ar + 8 * i);
          float4 a1 = *(const float4*)(Ar + 8 * i + 4);
          v[0] = a0.x; v[1] = a0.y; v[2] = a0.z; v[3] = a0.w;
          v[4] = a1.x; v[5] = a1.y; v[6] = a1.z; v[7] = a1.w;
        }
      } else {
#pragma unroll
        for (int j = 0; j < 8; ++j) v[j] = 0.f;
      }
      short8v hi, lo;
#pragma unroll
      for (int j = 0; j < 8; ++j) { short h_, l_; split2(v[j], h_, l_); hi[j] = h_; lo[j] = l_; }
      *(short8v*)swz(Ah, rl, p * 4 + i) = hi;
      *(short8v*)swz(Al, rl, p * 4 + i) = lo;
    }
  }
  int w = t >> 6, lane = t & 63;
  int m0 = w * 16;
  int lm = lane & 15, lq = lane >> 4;
  float4v acc[8];
#pragma unroll
  for (int j = 0; j < 8; ++j) acc[j] = (float4v){0.f, 0.f, 0.f, 0.f};

  for (int half = 0; half < 2; ++half) {
    __syncthreads();
    {
#pragma unroll
      for (int i = 0; i < 4; ++i) {
        int g = i * 256 + t;
        int n = g >> 3, kc = g & 7;
        size_t off = (size_t)n * 128 + half * 64 + kc * 8;
        *(short8v*)swz8(Wh, n, kc) = *(const short8v*)(Wth + off);
        *(short8v*)swz8(Wl, n, kc) = *(const short8v*)(Wtl + off);
      }
    }
    __syncthreads();
#pragma unroll
    for (int kk = 0; kk < 2; ++kk) {
      int ach = (half * 2 + kk) * 4 + lq;
      int wch = kk * 4 + lq;
      short8v ah = *(const short8v*)swz(Ah, m0 + lm, ach);
      short8v al = *(const short8v*)swz(Al, m0 + lm, ach);
#pragma unroll
      for (int j = 0; j < 8; ++j) {
        short8v bh = *(const short8v*)swz8(Wh, j * 16 + lm, wch);
        short8v bl = *(const short8v*)swz8(Wl, j * 16 + lm, wch);
        acc[j] = __builtin_amdgcn_mfma_f32_16x16x32_bf16(ah, bh, acc[j], 0, 0, 0);
        acc[j] = __builtin_amdgcn_mfma_f32_16x16x32_bf16(al, bh, acc[j], 0, 0, 0);
        acc[j] = __builtin_amdgcn_mfma_f32_16x16x32_bf16(ah, bl, acc[j], 0, 0, 0);
      }
    }
  }
#pragma unroll
  for (int j = 0; j < 8; ++j) {
    int n = j * 16 + lm;
    float bv = bias ? bias[n] : 0.f;
#pragma unroll
    for (int r = 0; r < 4; ++r) {
      int m = r0 + m0 + lq * 4 + r;
      if (m >= M) continue;
      float v = acc[j][r] + bv;
      if (skip) v += (float)skip[(size_t)m * C + n];
      if (relu) v = fmaxf(v, 0.f);
      out[(size_t)m * C + n] = (_Float16)v;
    }
  }
}

// ---------------- fused edge MLP (fp16, CSR order) -----------------------
// P/Q fp16 (256B/row gather), e1 = relu(P+Q) fp32->fp16 in 16KB LDS,
// single f16 MFMA per tile, W from fragment-major fp16 table (L1/L2-hot).
__global__ __launch_bounds__(256, 6)
void k_edge(const _Float16* __restrict__ P, const _Float16* __restrict__ Q,
            const int2* __restrict__ epair, const _Float16* __restrict__ Wf,
            const float* __restrict__ b1, const float* __restrict__ w2,
            const float* __restrict__ b2, float* __restrict__ tmpout, int E) {
  __shared__ __align__(16) _Float16 Et[64 * 128];
  int t = threadIdx.x;
  int p0 = blockIdx.x * 64;
  {
    int el = t >> 2, p4 = t & 3;
    int p = p0 + el;
    if (p >= E) p = E - 1;
    int2 rc = epair[p];
    const _Float16* Pp = P + (size_t)rc.x * C + p4 * 32;
    const _Float16* Qp = Q + (size_t)rc.y * C + p4 * 32;
#pragma unroll
    for (int i = 0; i < 4; ++i) {
      half8v a = *(const half8v*)(Pp + 8 * i);
      half8v b = *(const half8v*)(Qp + 8 * i);
      half8v o;
#pragma unroll
      for (int j = 0; j < 8; ++j)
        o[j] = (_Float16)fmaxf((float)a[j] + (float)b[j], 0.f);
      *(half8v*)swzh(Et, el, p4 * 4 + i) = o;
    }
  }
  __syncthreads();

  int w = t >> 6, lane = t & 63;
  int m0 = w * 16;
  int lm = lane & 15, lq = lane >> 4;
  float4v acc[8];
#pragma unroll
  for (int j = 0; j < 8; ++j) acc[j] = (float4v){0.f, 0.f, 0.f, 0.f};

#pragma unroll
  for (int kk = 0; kk < 4; ++kk) {
    int ch = kk * 4 + lq;
    half8v ah = *(const half8v*)swzh(Et, m0 + lm, ch);
#pragma unroll
    for (int j = 0; j < 8; ++j) {
      half8v b = *(const half8v*)(Wf + (((kk * 8 + j) * 64 + lane) << 3));
      acc[j] = __builtin_amdgcn_mfma_f32_16x16x32_f16(ah, b, acc[j], 0, 0, 0);
    }
  }

  float partv[4] = {0.f, 0.f, 0.f, 0.f};
#pragma unroll
  for (int j = 0; j < 8; ++j) {
    int n = j * 16 + lm;
    float b1v = b1[n], w2v = w2[n];
#pragma unroll
    for (int r = 0; r < 4; ++r) {
      float e2 = fmaxf(acc[j][r] + b1v, 0.f);
      partv[r] = fmaf(e2, w2v, partv[r]);
    }
  }
#pragma unroll
  for (int off = 1; off < 16; off <<= 1) {
#pragma unroll
    for (int r = 0; r < 4; ++r) partv[r] += __shfl_xor(partv[r], off, 64);
  }
  if (lm == 0) {
    float bb = b2[0];
#pragma unroll
    for (int r = 0; r < 4; ++r) {
      int p = p0 + m0 + lq * 4 + r;
      if (p < E) tmpout[p] = partv[r] + bb;  // coalesced (CSR order)
    }
  }
}

// ---------------- permute: out[e] = tmp[inv[e]] --------------------------
__global__ void k_perm(const float* __restrict__ tmp, const int* __restrict__ inv,
                       float* __restrict__ out, int E) {
  int e = blockIdx.x * 256 + threadIdx.x;
  if (e < E) out[e] = tmp[inv[e]];
}

// ---------------- host ---------------------------------------------------
extern "C" void kernel_launch(void* const* d_in, const int* in_sizes, int n_in,
                              void* d_out, int out_size, void* d_ws, size_t ws_size,
                              hipStream_t stream) {
  const float* x       = (const float*)d_in[0];
  const int*   ei      = (const int*)d_in[1];
  const float* convs_W = (const float*)d_in[2];
  const float* convs_b = (const float*)d_in[3];
  const float* fc0_W   = (const float*)d_in[4];
  const float* fc0_b   = (const float*)d_in[5];
  const float* fc1_W   = (const float*)d_in[6];
  const float* fc1_b   = (const float*)d_in[7];
  const float* fc2_W   = (const float*)d_in[8];
  const float* fc2_b   = (const float*)d_in[9];
  float* out = (float*)d_out;

  const int N = in_sizes[0] / C;        // 50000
  const int E = in_sizes[1] / 2;        // 1600000
  const int L = in_sizes[2] / (C * C);  // 8
  const int* row = ei;
  const int* col = ei + E;

  char* wp = (char*)d_ws;
  auto carve = [&](size_t bytes) {
    char* p = wp; wp += (bytes + 255) & ~(size_t)255; return p;
  };
  int*      cnt    = (int*)carve((size_t)N * 4);
  int*      indptr = (int*)carve((size_t)(N + 1) * 4);
  int*      cursor = (int*)carve((size_t)N * 4);
  float*    dis    = (float*)carve((size_t)N * 4);
  int2*     emeta  = (int2*)carve((size_t)E * 8);
  int2*     epair  = (int2*)carve((size_t)E * 8);
  int*      inv    = (int*)carve((size_t)E * 4);
  float*    tmpout = (float*)carve((size_t)E * 4);
  _Float16* Wf     = (_Float16*)carve((size_t)C * C * 2);
  ushort*   Wth    = (ushort*)carve((size_t)10 * C * C * 2);
  ushort*   Wtl    = (ushort*)carve((size_t)10 * C * C * 2);
  _Float16* xh     = (_Float16*)carve((size_t)N * C * 2);
  _Float16* h0     = (_Float16*)carve((size_t)N * C * 2);
  _Float16* h1     = (_Float16*)carve((size_t)N * C * 2);
  float*    aggb   = (float*)carve((size_t)N * C * 4);
  _Float16* Pm     = (_Float16*)carve((size_t)N * C * 2);
  _Float16* Qm     = (_Float16*)carve((size_t)N * C * 2);

  hipMemsetAsync(cnt, 0, (size_t)N * 4, stream);
  k_degree<<<(E + 255) / 256, 256, 0, stream>>>(col, cnt, E);
  k_scan<<<1, 1024, 0, stream>>>(cnt, dis, indptr, cursor, N);
  k_csrfill<<<(E + 255) / 256, 256, 0, stream>>>(row, col, dis, cursor,
                                                 emeta, epair, inv, E);
  k_prepwf<<<C * C / 256, 256, 0, stream>>>(fc1_W, Wf);
  k_prepw2<<<10 * C * C / 256, 256, 0, stream>>>(convs_W, fc0_W, Wth, Wtl);
  k_cvt<<<(N * C / 4 + 255) / 256, 256, 0, stream>>>(x, xh, N * C / 4);

  int aggBlocks  = (N * 64 + 255) / 256;
  int gemmBlocks = (N + 63) / 64;
  const int MSZ = C * C;

  // layer 0 (no skip)
  k_agg<<<aggBlocks, 256, 0, stream>>>(xh, indptr, emeta, dis, aggb, N);
  k_gemm_mfma<<<gemmBlocks, 256, 0, stream>>>(aggb, 0, Wth, Wtl, convs_b,
                                              nullptr, h0, N, 1);
  _Float16* hcur = h0; _Float16* hoth = h1;
  for (int l = 1; l < L; ++l) {
    k_agg<<<aggBlocks, 256, 0, stream>>>(hcur, indptr, emeta, dis, aggb, N);
    k_gemm_mfma<<<gemmBlocks, 256, 0, stream>>>(aggb, 0, Wth + (size_t)l * MSZ,
                                                Wtl + (size_t)l * MSZ,
                                                convs_b + (size_t)l * C, hcur,
                                                hoth, N, 1);
    _Float16* tmp = hcur; hcur = hoth; hoth = tmp;
  }
  // edge MLP: P = h@fc0_W[:128], Q = h@fc0_W[128:] + b0
  k_gemm_mfma<<<gemmBlocks, 256, 0, stream>>>(hcur, 1, Wth + (size_t)8 * MSZ,
                                              Wtl + (size_t)8 * MSZ, nullptr,
                                              nullptr, Pm, N, 0);
  k_gemm_mfma<<<gemmBlocks, 256, 0, stream>>>(hcur, 1, Wth + (size_t)9 * MSZ,
                                              Wtl + (size_t)9 * MSZ, fc0_b,
                                              nullptr, Qm, N, 0);
  k_edge<<<(E + 63) / 64, 256, 0, stream>>>(Pm, Qm, epair, Wf, fc1_b,
                                            fc2_W, fc2_b, tmpout, E);
  k_perm<<<(E + 255) / 256, 256, 0, stream>>>(tmpout, inv, out, E);
}

// Round 9
// 1336.322 us; speedup vs baseline: 1.4744x; 1.0093x over previous
//
#include <hip/hip_runtime.h>

#define C 128

typedef __attribute__((ext_vector_type(8))) short short8v;
typedef __attribute__((ext_vector_type(4))) float float4v;
typedef _Float16 half8v __attribute__((ext_vector_type(8)));
typedef _Float16 half4v __attribute__((ext_vector_type(4)));
typedef _Float16 half2v __attribute__((ext_vector_type(2)));

__device__ __forceinline__ ushort f2bf(float f) {
  union { float f; uint u; } v; v.f = f;
  uint u = v.u;
  return (ushort)((u + 0x7FFF + ((u >> 16) & 1)) >> 16);  // RNE
}
__device__ __forceinline__ float bf2f(ushort s) {
  union { uint u; float f; } v; v.u = ((uint)s) << 16; return v.f;
}
// truncation hi/lo split: pair-exact to 2^-16 rel; hi never used without lo
__device__ __forceinline__ void split2(float f, short& hi, short& lo) {
  union { float f; uint u; } v; v.f = f;
  uint uh = v.u & 0xFFFF0000u;
  hi = (short)(uh >> 16);
  union { uint u; float f; } w; w.u = uh;
  union { float f; uint u; } x; x.f = f - w.f;
  lo = (short)(x.u >> 16);
}

// LDS swizzles (units = elements; row stride 128 elems, 16 chunks of 8 / 8 chunks)
__device__ __forceinline__ short* swz(short* base, int row, int chunk) {
  return base + row * 128 + ((chunk ^ (row & 15)) << 3);
}
__device__ __forceinline__ short* swz8(short* base, int row, int chunk) {
  return base + row * 64 + ((chunk ^ (row & 7)) << 3);
}
__device__ __forceinline__ _Float16* swzh(_Float16* base, int row, int chunk) {
  return base + row * 128 + ((chunk ^ (row & 15)) << 3);
}

// ---------------- degree count ------------------------------------------
__global__ void k_degree(const int* __restrict__ col, int* __restrict__ cnt, int E) {
  int e = blockIdx.x * blockDim.x + threadIdx.x;
  if (e < E) atomicAdd(&cnt[col[e]], 1);
}

// ---------------- single-block scan -------------------------------------
__global__ void k_scan(const int* __restrict__ cnt, float* __restrict__ dis,
                       int* __restrict__ indptr, int* __restrict__ cursor, int N) {
  __shared__ int sb[1024];
  int t = threadIdx.x;
  int chunk = (N + 1023) >> 10;
  int lo = t * chunk, hi = min(lo + chunk, N);
  int sum = 0;
  for (int i = lo; i < hi; ++i) sum += cnt[i];
  sb[t] = sum;
  __syncthreads();
  for (int off = 1; off < 1024; off <<= 1) {
    int v = (t >= off) ? sb[t - off] : 0;
    __syncthreads();
    sb[t] += v;
    __syncthreads();
  }
  int run = sb[t] - sum;
  for (int i = lo; i < hi; ++i) {
    indptr[i] = run; cursor[i] = run;
    dis[i] = rsqrtf((float)(cnt[i] + 1));
    run += cnt[i];
  }
  if (lo < N && hi == N) indptr[N] = run;
}

// ---------------- CSR fill ----------------------------------------------
__global__ void k_csrfill(const int* __restrict__ row, const int* __restrict__ col,
                          const float* __restrict__ dis, int* __restrict__ cursor,
                          int2* __restrict__ emeta, int2* __restrict__ epair,
                          int* __restrict__ inv, int E) {
  int e = blockIdx.x * blockDim.x + threadIdx.x;
  if (e >= E) return;
  int r = row[e], c = col[e];
  int pos = atomicAdd(&cursor[c], 1);
  float nrm = dis[r] * dis[c];
  emeta[pos] = make_int2(r, __float_as_int(nrm));
  epair[pos] = make_int2(r, c);
  inv[e] = pos;
}

// ---------------- x fp32 -> fp16 ----------------------------------------
__global__ void k_cvt(const float* __restrict__ x, _Float16* __restrict__ xh, int n4) {
  int i = blockIdx.x * 256 + threadIdx.x;
  if (i >= n4) return;
  float4 v = ((const float4*)x)[i];
  half4v o = {(_Float16)v.x, (_Float16)v.y, (_Float16)v.z, (_Float16)v.w};
  *(half4v*)(xh + i * 4) = o;
}

// ---------------- W1 -> fp16 fragment-major table -----------------------
__global__ void k_prepwf(const float* __restrict__ W1, _Float16* __restrict__ Wf) {
  int idx = blockIdx.x * 256 + threadIdx.x;  // 16384
  int e = idx & 7, lane = (idx >> 3) & 63, j = (idx >> 9) & 7, kk = idx >> 12;
  int n = j * 16 + (lane & 15);
  int k = (kk * 4 + (lane >> 4)) * 8 + e;
  Wf[idx] = (_Float16)W1[k * C + n];
}

// ---------------- conv/fc0 W^T -> bf16 hi/lo (10 matrices) --------------
__global__ void k_prepw2(const float* __restrict__ convs_W,
                         const float* __restrict__ fc0_W,
                         ushort* __restrict__ Wth, ushort* __restrict__ Wtl) {
  int g = blockIdx.x * 256 + threadIdx.x;  // [0, 10*16384)
  int mat = g >> 14, idx = g & 16383;
  int n = idx >> 7, k = idx & 127;
  const float* src = (mat < 8) ? convs_W + ((size_t)mat << 14)
                               : fc0_W + ((size_t)(mat - 8) << 14);
  float v = src[k * C + n];
  ushort h = f2bf(v);
  Wth[g] = h;
  Wtl[g] = f2bf(v - bf2f(h));
}

// ---------------- aggregation (fp16 h), 4 edges per gather instr --------
// Wave per node. lane = (edge-slot g16 = lane>>4, channel-octet c8 = lane&15).
// Each lane does one 16B half8 load -> 1024B = 4 h-rows per instruction.
// shfl_xor(16,32) combines edge groups; lanes 0-15 add self-loop + store.
__global__ __launch_bounds__(256)
void k_agg(const _Float16* __restrict__ h, const int* __restrict__ indptr,
           const int2* __restrict__ emeta, const float* __restrict__ dis,
           float* __restrict__ agg, int N) {
  int w = (blockIdx.x * 256 + threadIdx.x) >> 6;
  int lane = threadIdx.x & 63;
  if (w >= N) return;
  int g16 = lane >> 4, c8 = lane & 15;
  int s = indptr[w], e = indptr[w + 1];
  float acc[8];
#pragma unroll
  for (int j = 0; j < 8; ++j) acc[j] = 0.f;

  int i = s;
  for (; i + 16 <= e; i += 16) {  // 4 kB-gathers in flight
    int2 m[4];
#pragma unroll
    for (int u = 0; u < 4; ++u) m[u] = emeta[i + u * 4 + g16];
    half8v hv[4];
#pragma unroll
    for (int u = 0; u < 4; ++u)
      hv[u] = *(const half8v*)(h + (size_t)m[u].x * C + c8 * 8);
#pragma unroll
    for (int u = 0; u < 4; ++u) {
      float nn = __int_as_float(m[u].y);
#pragma unroll
      for (int j = 0; j < 8; ++j) acc[j] += nn * (float)hv[u][j];
    }
  }
  for (; i + 4 <= e; i += 4) {
    int2 m = emeta[i + g16];
    half8v hv = *(const half8v*)(h + (size_t)m.x * C + c8 * 8);
    float nn = __int_as_float(m.y);
#pragma unroll
    for (int j = 0; j < 8; ++j) acc[j] += nn * (float)hv[j];
  }
  if (i < e) {  // tail 1..3: masked lanes contribute 0
    int idx = i + g16;
    int2 m = make_int2(w, 0);
    if (idx < e) m = emeta[idx];
    half8v hv = *(const half8v*)(h + (size_t)m.x * C + c8 * 8);
    float nn = __int_as_float(m.y);
#pragma unroll
    for (int j = 0; j < 8; ++j) acc[j] += nn * (float)hv[j];
  }
  // combine 4 edge groups
#pragma unroll
  for (int j = 0; j < 8; ++j) {
    acc[j] += __shfl_xor(acc[j], 16, 64);
    acc[j] += __shfl_xor(acc[j], 32, 64);
  }
  if (lane < 16) {
    float dv = dis[w];
    float dv2 = dv * dv;
    half8v hs = *(const half8v*)(h + (size_t)w * C + lane * 8);
    float4 o0, o1;
    o0.x = acc[0] + dv2 * (float)hs[0]; o0.y = acc[1] + dv2 * (float)hs[1];
    o0.z = acc[2] + dv2 * (float)hs[2]; o0.w = acc[3] + dv2 * (float)hs[3];
    o1.x = acc[4] + dv2 * (float)hs[4]; o1.y = acc[5] + dv2 * (float)hs[5];
    o1.z = acc[6] + dv2 * (float)hs[6]; o1.w = acc[7] + dv2 * (float)hs[7];
    *(float4*)(agg + (size_t)w * C + lane * 8) = o0;
    *(float4*)(agg + (size_t)w * C + lane * 8 + 4) = o1;
  }
}

// ---------------- MFMA GEMM: out_fp16[M,128] = op(A @ W) ----------------
__global__ __launch_bounds__(256, 2)
void k_gemm_mfma(const void* __restrict__ Av, int a_f16,
                 const ushort* __restrict__ Wth, const ushort* __restrict__ Wtl,
                 const float* __restrict__ bias, const _Float16* __restrict__ skip,
                 _Float16* __restrict__ out, int M, int relu) {
  __shared__ __align__(16) short Ah[64 * 128];
  __shared__ __align__(16) short Al[64 * 128];
  __shared__ __align__(16) short Wh[128 * 64];
  __shared__ __align__(16) short Wl[128 * 64];
  int t = threadIdx.x;
  int r0 = blockIdx.x * 64;
  {
    int rl = t >> 2, p = t & 3;
    int r = r0 + rl;
#pragma unroll
    for (int i = 0; i < 4; ++i) {
      float v[8];
      if (r < M) {
        if (a_f16) {
          const _Float16* Ar = (const _Float16*)Av + (size_t)r * C + p * 32;
          half8v a = *(const half8v*)(Ar + 8 * i);
#pragma unroll
          for (int j = 0; j < 8; ++j) v[j] = (float)a[j];
        } else {
          const float* Ar = (const float*)Av + (size_t)r * C + p * 32;
          float4 a0 = *(const float4*)(Ar + 8 * i);
          float4 a1 = *(const float4*)(Ar + 8 * i + 4);
          v[0] = a0.x; v[1] = a0.y; v[2] = a0.z; v[3] = a0.w;
          v[4] = a1.x; v[5] = a1.y; v[6] = a1.z; v[7] = a1.w;
        }
      } else {
#pragma unroll
        for (int j = 0; j < 8; ++j) v[j] = 0.f;
      }
      short8v hi, lo;
#pragma unroll
      for (int j = 0; j < 8; ++j) { short h_, l_; split2(v[j], h_, l_); hi[j] = h_; lo[j] = l_; }
      *(short8v*)swz(Ah, rl, p * 4 + i) = hi;
      *(short8v*)swz(Al, rl, p * 4 + i) = lo;
    }
  }
  int w = t >> 6, lane = t & 63;
  int m0 = w * 16;
  int lm = lane & 15, lq = lane >> 4;
  float4v acc[8];
#pragma unroll
  for (int j = 0; j < 8; ++j) acc[j] = (float4v){0.f, 0.f, 0.f, 0.f};

  for (int half = 0; half < 2; ++half) {
    __syncthreads();
    {
#pragma unroll
      for (int i = 0; i < 4; ++i) {
        int g = i * 256 + t;
        int n = g >> 3, kc = g & 7;
        size_t off = (size_t)n * 128 + half * 64 + kc * 8;
        *(short8v*)swz8(Wh, n, kc) = *(const short8v*)(Wth + off);
        *(short8v*)swz8(Wl, n, kc) = *(const short8v*)(Wtl + off);
      }
    }
    __syncthreads();
#pragma unroll
    for (int kk = 0; kk < 2; ++kk) {
      int ach = (half * 2 + kk) * 4 + lq;
      int wch = kk * 4 + lq;
      short8v ah = *(const short8v*)swz(Ah, m0 + lm, ach);
      short8v al = *(const short8v*)swz(Al, m0 + lm, ach);
#pragma unroll
      for (int j = 0; j < 8; ++j) {
        short8v bh = *(const short8v*)swz8(Wh, j * 16 + lm, wch);
        short8v bl = *(const short8v*)swz8(Wl, j * 16 + lm, wch);
        acc[j] = __builtin_amdgcn_mfma_f32_16x16x32_bf16(ah, bh, acc[j], 0, 0, 0);
        acc[j] = __builtin_amdgcn_mfma_f32_16x16x32_bf16(al, bh, acc[j], 0, 0, 0);
        acc[j] = __builtin_amdgcn_mfma_f32_16x16x32_bf16(ah, bl, acc[j], 0, 0, 0);
      }
    }
  }
#pragma unroll
  for (int j = 0; j < 8; ++j) {
    int n = j * 16 + lm;
    float bv = bias ? bias[n] : 0.f;
#pragma unroll
    for (int r = 0; r < 4; ++r) {
      int m = r0 + m0 + lq * 4 + r;
      if (m >= M) continue;
      float v = acc[j][r] + bv;
      if (skip) v += (float)skip[(size_t)m * C + n];
      if (relu) v = fmaxf(v, 0.f);
      out[(size_t)m * C + n] = (_Float16)v;
    }
  }
}

// ---------------- fused edge MLP (fp16, CSR order) -----------------------
// e1 staging uses native packed fp16 add/max (numerically identical to the
// fp32 path: single RNE16 rounding either way).
__global__ __launch_bounds__(256, 6)
void k_edge(const _Float16* __restrict__ P, const _Float16* __restrict__ Q,
            const int2* __restrict__ epair, const _Float16* __restrict__ Wf,
            const float* __restrict__ b1, const float* __restrict__ w2,
            const float* __restrict__ b2, float* __restrict__ tmpout, int E) {
  __shared__ __align__(16) _Float16 Et[64 * 128];
  int t = threadIdx.x;
  int p0 = blockIdx.x * 64;
  {
    int el = t >> 2, p4 = t & 3;
    int p = p0 + el;
    if (p >= E) p = E - 1;
    int2 rc = epair[p];
    const _Float16* Pp = P + (size_t)rc.x * C + p4 * 32;
    const _Float16* Qp = Q + (size_t)rc.y * C + p4 * 32;
#pragma unroll
    for (int i = 0; i < 4; ++i) {
      half8v a = *(const half8v*)(Pp + 8 * i);
      half8v b = *(const half8v*)(Qp + 8 * i);
      half8v sum = a + b;           // v_pk_add_f16
      half8v o;
#pragma unroll
      for (int j = 0; j < 8; ++j) {
        _Float16 v = sum[j];
        o[j] = (v > (_Float16)0.f) ? v : (_Float16)0.f;  // v_pk_max_f16
      }
      *(half8v*)swzh(Et, el, p4 * 4 + i) = o;
    }
  }
  __syncthreads();

  int w = t >> 6, lane = t & 63;
  int m0 = w * 16;
  int lm = lane & 15, lq = lane >> 4;
  float4v acc[8];
#pragma unroll
  for (int j = 0; j < 8; ++j) acc[j] = (float4v){0.f, 0.f, 0.f, 0.f};

#pragma unroll
  for (int kk = 0; kk < 4; ++kk) {
    int ch = kk * 4 + lq;
    half8v ah = *(const half8v*)swzh(Et, m0 + lm, ch);
#pragma unroll
    for (int j = 0; j < 8; ++j) {
      half8v b = *(const half8v*)(Wf + (((kk * 8 + j) * 64 + lane) << 3));
      acc[j] = __builtin_amdgcn_mfma_f32_16x16x32_f16(ah, b, acc[j], 0, 0, 0);
    }
  }

  float partv[4] = {0.f, 0.f, 0.f, 0.f};
#pragma unroll
  for (int j = 0; j < 8; ++j) {
    int n = j * 16 + lm;
    float b1v = b1[n], w2v = w2[n];
#pragma unroll
    for (int r = 0; r < 4; ++r) {
      float e2 = fmaxf(acc[j][r] + b1v, 0.f);
      partv[r] = fmaf(e2, w2v, partv[r]);
    }
  }
#pragma unroll
  for (int off = 1; off < 16; off <<= 1) {
#pragma unroll
    for (int r = 0; r < 4; ++r) partv[r] += __shfl_xor(partv[r], off, 64);
  }
  if (lm == 0) {
    float bb = b2[0];
#pragma unroll
    for (int r = 0; r < 4; ++r) {
      int p = p0 + m0 + lq * 4 + r;
      if (p < E) tmpout[p] = partv[r] + bb;  // coalesced (CSR order)
    }
  }
}

// ---------------- permute: out[e] = tmp[inv[e]] --------------------------
__global__ void k_perm(const float* __restrict__ tmp, const int* __restrict__ inv,
                       float* __restrict__ out, int E) {
  int e = blockIdx.x * 256 + threadIdx.x;
  if (e < E) out[e] = tmp[inv[e]];
}

// ---------------- host ---------------------------------------------------
extern "C" void kernel_launch(void* const* d_in, const int* in_sizes, int n_in,
                              void* d_out, int out_size, void* d_ws, size_t ws_size,
                              hipStream_t stream) {
  const float* x       = (const float*)d_in[0];
  const int*   ei      = (const int*)d_in[1];
  const float* convs_W = (const float*)d_in[2];
  const float* convs_b = (const float*)d_in[3];
  const float* fc0_W   = (const float*)d_in[4];
  const float* fc0_b   = (const float*)d_in[5];
  const float* fc1_W   = (const float*)d_in[6];
  const float* fc1_b   = (const float*)d_in[7];
  const float* fc2_W   = (const float*)d_in[8];
  const float* fc2_b   = (const float*)d_in[9];
  float* out = (float*)d_out;

  const int N = in_sizes[0] / C;        // 50000
  const int E = in_sizes[1] / 2;        // 1600000
  const int L = in_sizes[2] / (C * C);  // 8
  const int* row = ei;
  const int* col = ei + E;

  char* wp = (char*)d_ws;
  auto carve = [&](size_t bytes) {
    char* p = wp; wp += (bytes + 255) & ~(size_t)255; return p;
  };
  int*      cnt    = (int*)carve((size_t)N * 4);
  int*      indptr = (int*)carve((size_t)(N + 1) * 4);
  int*      cursor = (int*)carve((size_t)N * 4);
  float*    dis    = (float*)carve((size_t)N * 4);
  int2*     emeta  = (int2*)carve((size_t)E * 8);
  int2*     epair  = (int2*)carve((size_t)E * 8);
  int*      inv    = (int*)carve((size_t)E * 4);
  float*    tmpout = (float*)carve((size_t)E * 4);
  _Float16* Wf     = (_Float16*)carve((size_t)C * C * 2);
  ushort*   Wth    = (ushort*)carve((size_t)10 * C * C * 2);
  ushort*   Wtl    = (ushort*)carve((size_t)10 * C * C * 2);
  _Float16* xh     = (_Float16*)carve((size_t)N * C * 2);
  _Float16* h0     = (_Float16*)carve((size_t)N * C * 2);
  _Float16* h1     = (_Float16*)carve((size_t)N * C * 2);
  float*    aggb   = (float*)carve((size_t)N * C * 4);
  _Float16* Pm     = (_Float16*)carve((size_t)N * C * 2);
  _Float16* Qm     = (_Float16*)carve((size_t)N * C * 2);

  hipMemsetAsync(cnt, 0, (size_t)N * 4, stream);
  k_degree<<<(E + 255) / 256, 256, 0, stream>>>(col, cnt, E);
  k_scan<<<1, 1024, 0, stream>>>(cnt, dis, indptr, cursor, N);
  k_csrfill<<<(E + 255) / 256, 256, 0, stream>>>(row, col, dis, cursor,
                                                 emeta, epair, inv, E);
  k_prepwf<<<C * C / 256, 256, 0, stream>>>(fc1_W, Wf);
  k_prepw2<<<10 * C * C / 256, 256, 0, stream>>>(convs_W, fc0_W, Wth, Wtl);
  k_cvt<<<(N * C / 4 + 255) / 256, 256, 0, stream>>>(x, xh, N * C / 4);

  int aggBlocks  = (N * 64 + 255) / 256;
  int gemmBlocks = (N + 63) / 64;
  const int MSZ = C * C;

  // layer 0 (no skip)
  k_agg<<<aggBlocks, 256, 0, stream>>>(xh, indptr, emeta, dis, aggb, N);
  k_gemm_mfma<<<gemmBlocks, 256, 0, stream>>>(aggb, 0, Wth, Wtl, convs_b,
                                              nullptr, h0, N, 1);
  _Float16* hcur = h0; _Float16* hoth = h1;
  for (int l = 1; l < L; ++l) {
    k_agg<<<aggBlocks, 256, 0, stream>>>(hcur, indptr, emeta, dis, aggb, N);
    k_gemm_mfma<<<gemmBlocks, 256, 0, stream>>>(aggb, 0, Wth + (size_t)l * MSZ,
                                                Wtl + (size_t)l * MSZ,
                                                convs_b + (size_t)l * C, hcur,
                                                hoth, N, 1);
    _Float16* tmp = hcur; hcur = hoth; hoth = tmp;
  }
  // edge MLP: P = h@fc0_W[:128], Q = h@fc0_W[128:] + b0
  k_gemm_mfma<<<gemmBlocks, 256, 0, stream>>>(hcur, 1, Wth + (size_t)8 * MSZ,
                                              Wtl + (size_t)8 * MSZ, nullptr,
                                              nullptr, Pm, N, 0);
  k_gemm_mfma<<<gemmBlocks, 256, 0, stream>>>(hcur, 1, Wth + (size_t)9 * MSZ,
                                              Wtl + (size_t)9 * MSZ, fc0_b,
                                              nullptr, Qm, N, 0);
  k_edge<<<(E + 63) / 64, 256, 0, stream>>>(Pm, Qm, epair, Wf, fc1_b,
                                            fc2_W, fc2_b, tmpout, E);
  k_perm<<<(E + 255) / 256, 256, 0, stream>>>(tmpout, inv, out, E);
}

// Round 10
// 1231.222 us; speedup vs baseline: 1.6003x; 1.0854x over previous
//
#include <hip/hip_runtime.h>

#define C 128

typedef __attribute__((ext_vector_type(4))) float float4v;
typedef _Float16 half8v __attribute__((ext_vector_type(8)));
typedef _Float16 half4v __attribute__((ext_vector_type(4)));
typedef _Float16 half2v __attribute__((ext_vector_type(2)));

// LDS swizzle (fp16, row stride 128 elems, 16 chunks of 8)
__device__ __forceinline__ _Float16* swzh(_Float16* base, int row, int chunk) {
  return base + row * 128 + ((chunk ^ (row & 15)) << 3);
}

// ---------------- degree count ------------------------------------------
__global__ void k_degree(const int* __restrict__ col, int* __restrict__ cnt, int E) {
  int e = blockIdx.x * blockDim.x + threadIdx.x;
  if (e < E) atomicAdd(&cnt[col[e]], 1);
}

// ---------------- single-block scan -------------------------------------
__global__ void k_scan(const int* __restrict__ cnt, float* __restrict__ dis,
                       int* __restrict__ indptr, int* __restrict__ cursor, int N) {
  __shared__ int sb[1024];
  int t = threadIdx.x;
  int chunk = (N + 1023) >> 10;
  int lo = t * chunk, hi = min(lo + chunk, N);
  int sum = 0;
  for (int i = lo; i < hi; ++i) sum += cnt[i];
  sb[t] = sum;
  __syncthreads();
  for (int off = 1; off < 1024; off <<= 1) {
    int v = (t >= off) ? sb[t - off] : 0;
    __syncthreads();
    sb[t] += v;
    __syncthreads();
  }
  int run = sb[t] - sum;
  for (int i = lo; i < hi; ++i) {
    indptr[i] = run; cursor[i] = run;
    dis[i] = rsqrtf((float)(cnt[i] + 1));
    run += cnt[i];
  }
  if (lo < N && hi == N) indptr[N] = run;
}

// ---------------- CSR fill ----------------------------------------------
__global__ void k_csrfill(const int* __restrict__ row, const int* __restrict__ col,
                          const float* __restrict__ dis, int* __restrict__ cursor,
                          int2* __restrict__ emeta, int2* __restrict__ epair,
                          int* __restrict__ inv, int E) {
  int e = blockIdx.x * blockDim.x + threadIdx.x;
  if (e >= E) return;
  int r = row[e], c = col[e];
  int pos = atomicAdd(&cursor[c], 1);
  float nrm = dis[r] * dis[c];
  emeta[pos] = make_int2(r, __float_as_int(nrm));
  epair[pos] = make_int2(r, c);
  inv[e] = pos;
}

// ---------------- x fp32 -> fp16 ----------------------------------------
__global__ void k_cvt(const float* __restrict__ x, _Float16* __restrict__ xh, int n4) {
  int i = blockIdx.x * 256 + threadIdx.x;
  if (i >= n4) return;
  float4 v = ((const float4*)x)[i];
  half4v o = {(_Float16)v.x, (_Float16)v.y, (_Float16)v.z, (_Float16)v.w};
  *(half4v*)(xh + i * 4) = o;
}

// ---------------- W1 -> fp16 fragment-major table (fc1) ------------------
__global__ void k_prepwf(const float* __restrict__ W1, _Float16* __restrict__ Wf) {
  int idx = blockIdx.x * 256 + threadIdx.x;  // 16384
  int e = idx & 7, lane = (idx >> 3) & 63, j = (idx >> 9) & 7, kk = idx >> 12;
  int n = j * 16 + (lane & 15);
  int k = (kk * 4 + (lane >> 4)) * 8 + e;
  Wf[idx] = (_Float16)W1[k * C + n];
}

// ------- conv/fc0 W -> fragment-major fp16 hi + scaled-lo (10 mats) ------
// lo = fp16((W - hi) * 4096): scaling keeps lo normal (W~0.09 -> resid
// ~4e-5 < fp16 min-normal 6e-5 would denormal-flush in MFMA). Epilogue
// recombines acc_h + acc_l/4096 -> fp32-equivalent W.
__global__ void k_prepw2(const float* __restrict__ convs_W,
                         const float* __restrict__ fc0_W,
                         _Float16* __restrict__ Wfh, _Float16* __restrict__ Wfl) {
  int g = blockIdx.x * 256 + threadIdx.x;  // [0, 10*16384)
  int mat = g >> 14, idx = g & 16383;
  int e = idx & 7, lane = (idx >> 3) & 63, j = (idx >> 9) & 7, kk = idx >> 12;
  int n = j * 16 + (lane & 15);
  int k = (kk * 4 + (lane >> 4)) * 8 + e;
  const float* src = (mat < 8) ? convs_W + ((size_t)mat << 14)
                               : fc0_W + ((size_t)(mat - 8) << 14);
  float v = src[k * C + n];
  _Float16 h = (_Float16)v;
  Wfh[g] = h;
  Wfl[g] = (_Float16)((v - (float)h) * 4096.f);
}

// ---------------- aggregation (fp16 h -> fp16 agg) -----------------------
// Wave per node; lane = (edge-slot lane>>4, channel-octet lane&15); each
// lane: one 16B half8 load -> 1024B = 4 h-rows per instruction. fp32 accum.
__global__ __launch_bounds__(256)
void k_agg(const _Float16* __restrict__ h, const int* __restrict__ indptr,
           const int2* __restrict__ emeta, const float* __restrict__ dis,
           _Float16* __restrict__ agg, int N) {
  int w = (blockIdx.x * 256 + threadIdx.x) >> 6;
  int lane = threadIdx.x & 63;
  if (w >= N) return;
  int g16 = lane >> 4, c8 = lane & 15;
  int s = indptr[w], e = indptr[w + 1];
  float acc[8];
#pragma unroll
  for (int j = 0; j < 8; ++j) acc[j] = 0.f;

  int i = s;
  for (; i + 16 <= e; i += 16) {  // 4 kB-gathers in flight
    int2 m[4];
#pragma unroll
    for (int u = 0; u < 4; ++u) m[u] = emeta[i + u * 4 + g16];
    half8v hv[4];
#pragma unroll
    for (int u = 0; u < 4; ++u)
      hv[u] = *(const half8v*)(h + (size_t)m[u].x * C + c8 * 8);
#pragma unroll
    for (int u = 0; u < 4; ++u) {
      float nn = __int_as_float(m[u].y);
#pragma unroll
      for (int j = 0; j < 8; ++j) acc[j] += nn * (float)hv[u][j];
    }
  }
  for (; i + 4 <= e; i += 4) {
    int2 m = emeta[i + g16];
    half8v hv = *(const half8v*)(h + (size_t)m.x * C + c8 * 8);
    float nn = __int_as_float(m.y);
#pragma unroll
    for (int j = 0; j < 8; ++j) acc[j] += nn * (float)hv[j];
  }
  if (i < e) {  // tail 1..3: out-of-range lanes use norm 0
    int idx = i + g16;
    int2 m = make_int2(w, 0);
    if (idx < e) m = emeta[idx];
    half8v hv = *(const half8v*)(h + (size_t)m.x * C + c8 * 8);
    float nn = __int_as_float(m.y);
#pragma unroll
    for (int j = 0; j < 8; ++j) acc[j] += nn * (float)hv[j];
  }
#pragma unroll
  for (int j = 0; j < 8; ++j) {
    acc[j] += __shfl_xor(acc[j], 16, 64);
    acc[j] += __shfl_xor(acc[j], 32, 64);
  }
  if (lane < 16) {
    float dv = dis[w];
    float dv2 = dv * dv;
    half8v hs = *(const half8v*)(h + (size_t)w * C + lane * 8);
    half8v o;
#pragma unroll
    for (int j = 0; j < 8; ++j) o[j] = (_Float16)(acc[j] + dv2 * (float)hs[j]);
    *(half8v*)(agg + (size_t)w * C + lane * 8) = o;
  }
}

// ---------------- streaming f16 MFMA GEMM (no LDS, no barrier) ----------
// A fp16 streamed: one wave fragment-load = 16 rows x 64B contiguous = 16
// full lines. W from fragment-major fp16 hi/scaled-lo tables (L2-hot).
// out = op(A @ W): fp32-equivalent W via acc_h + acc_l/4096.
__global__ __launch_bounds__(256, 4)
void k_gemm_f16(const _Float16* __restrict__ A,
                const _Float16* __restrict__ Wfh, const _Float16* __restrict__ Wfl,
                const float* __restrict__ bias, const _Float16* __restrict__ skip,
                _Float16* __restrict__ out, int M, int relu) {
  int t = threadIdx.x;
  int r0 = blockIdx.x * 64;
  int w = t >> 6, lane = t & 63;
  int m0 = w * 16, lm = lane & 15, lq = lane >> 4;
  int row = r0 + m0 + lm;
  if (row >= M) row = M - 1;
  const _Float16* Ar = A + (size_t)row * C;

  float4v acch[8], accl[8];
#pragma unroll
  for (int j = 0; j < 8; ++j) {
    acch[j] = (float4v){0.f, 0.f, 0.f, 0.f};
    accl[j] = (float4v){0.f, 0.f, 0.f, 0.f};
  }
#pragma unroll
  for (int kk = 0; kk < 4; ++kk) {
    half8v a = *(const half8v*)(Ar + kk * 32 + lq * 8);
#pragma unroll
    for (int j = 0; j < 8; ++j) {
      int fi = ((kk * 8 + j) * 64 + lane) << 3;
      half8v bh = *(const half8v*)(Wfh + fi);
      half8v bl = *(const half8v*)(Wfl + fi);
      acch[j] = __builtin_amdgcn_mfma_f32_16x16x32_f16(a, bh, acch[j], 0, 0, 0);
      accl[j] = __builtin_amdgcn_mfma_f32_16x16x32_f16(a, bl, accl[j], 0, 0, 0);
    }
  }
#pragma unroll
  for (int j = 0; j < 8; ++j) {
    int n = j * 16 + lm;
    float bv = bias ? bias[n] : 0.f;
#pragma unroll
    for (int r = 0; r < 4; ++r) {
      int m = r0 + m0 + lq * 4 + r;
      if (m >= M) continue;
      float v = acch[j][r] + accl[j][r] * (1.f / 4096.f) + bv;
      if (skip) v += (float)skip[(size_t)m * C + n];
      if (relu) v = fmaxf(v, 0.f);
      out[(size_t)m * C + n] = (_Float16)v;
    }
  }
}

// ---------------- fused edge MLP (fp16, CSR order) -----------------------
__global__ __launch_bounds__(256, 6)
void k_edge(const _Float16* __restrict__ P, const _Float16* __restrict__ Q,
            const int2* __restrict__ epair, const _Float16* __restrict__ Wf,
            const float* __restrict__ b1, const float* __restrict__ w2,
            const float* __restrict__ b2, float* __restrict__ tmpout, int E) {
  __shared__ __align__(16) _Float16 Et[64 * 128];
  int t = threadIdx.x;
  int p0 = blockIdx.x * 64;
  {
    int el = t >> 2, p4 = t & 3;
    int p = p0 + el;
    if (p >= E) p = E - 1;
    int2 rc = epair[p];
    const _Float16* Pp = P + (size_t)rc.x * C + p4 * 32;
    const _Float16* Qp = Q + (size_t)rc.y * C + p4 * 32;
#pragma unroll
    for (int i = 0; i < 4; ++i) {
      half8v a = *(const half8v*)(Pp + 8 * i);
      half8v b = *(const half8v*)(Qp + 8 * i);
      half8v sum = a + b;
      half8v o;
#pragma unroll
      for (int j = 0; j < 8; ++j) {
        _Float16 v = sum[j];
        o[j] = (v > (_Float16)0.f) ? v : (_Float16)0.f;
      }
      *(half8v*)swzh(Et, el, p4 * 4 + i) = o;
    }
  }
  __syncthreads();

  int w = t >> 6, lane = t & 63;
  int m0 = w * 16;
  int lm = lane & 15, lq = lane >> 4;
  float4v acc[8];
#pragma unroll
  for (int j = 0; j < 8; ++j) acc[j] = (float4v){0.f, 0.f, 0.f, 0.f};

#pragma unroll
  for (int kk = 0; kk < 4; ++kk) {
    int ch = kk * 4 + lq;
    half8v ah = *(const half8v*)swzh(Et, m0 + lm, ch);
#pragma unroll
    for (int j = 0; j < 8; ++j) {
      half8v b = *(const half8v*)(Wf + (((kk * 8 + j) * 64 + lane) << 3));
      acc[j] = __builtin_amdgcn_mfma_f32_16x16x32_f16(ah, b, acc[j], 0, 0, 0);
    }
  }

  float partv[4] = {0.f, 0.f, 0.f, 0.f};
#pragma unroll
  for (int j = 0; j < 8; ++j) {
    int n = j * 16 + lm;
    float b1v = b1[n], w2v = w2[n];
#pragma unroll
    for (int r = 0; r < 4; ++r) {
      float e2 = fmaxf(acc[j][r] + b1v, 0.f);
      partv[r] = fmaf(e2, w2v, partv[r]);
    }
  }
#pragma unroll
  for (int off = 1; off < 16; off <<= 1) {
#pragma unroll
    for (int r = 0; r < 4; ++r) partv[r] += __shfl_xor(partv[r], off, 64);
  }
  if (lm == 0) {
    float bb = b2[0];
#pragma unroll
    for (int r = 0; r < 4; ++r) {
      int p = p0 + m0 + lq * 4 + r;
      if (p < E) tmpout[p] = partv[r] + bb;  // coalesced (CSR order)
    }
  }
}

// ---------------- permute: out[e] = tmp[inv[e]] --------------------------
__global__ void k_perm(const float* __restrict__ tmp, const int* __restrict__ inv,
                       float* __restrict__ out, int E) {
  int e = blockIdx.x * 256 + threadIdx.x;
  if (e < E) out[e] = tmp[inv[e]];
}

// ---------------- host ---------------------------------------------------
extern "C" void kernel_launch(void* const* d_in, const int* in_sizes, int n_in,
                              void* d_out, int out_size, void* d_ws, size_t ws_size,
                              hipStream_t stream) {
  const float* x       = (const float*)d_in[0];
  const int*   ei      = (const int*)d_in[1];
  const float* convs_W = (const float*)d_in[2];
  const float* convs_b = (const float*)d_in[3];
  const float* fc0_W   = (const float*)d_in[4];
  const float* fc0_b   = (const float*)d_in[5];
  const float* fc1_W   = (const float*)d_in[6];
  const float* fc1_b   = (const float*)d_in[7];
  const float* fc2_W   = (const float*)d_in[8];
  const float* fc2_b   = (const float*)d_in[9];
  float* out = (float*)d_out;

  const int N = in_sizes[0] / C;        // 50000
  const int E = in_sizes[1] / 2;        // 1600000
  const int L = in_sizes[2] / (C * C);  // 8
  const int* row = ei;
  const int* col = ei + E;

  char* wp = (char*)d_ws;
  auto carve = [&](size_t bytes) {
    char* p = wp; wp += (bytes + 255) & ~(size_t)255; return p;
  };
  int*      cnt    = (int*)carve((size_t)N * 4);
  int*      indptr = (int*)carve((size_t)(N + 1) * 4);
  int*      cursor = (int*)carve((size_t)N * 4);
  float*    dis    = (float*)carve((size_t)N * 4);
  int2*     emeta  = (int2*)carve((size_t)E * 8);
  int2*     epair  = (int2*)carve((size_t)E * 8);
  int*      inv    = (int*)carve((size_t)E * 4);
  float*    tmpout = (float*)carve((size_t)E * 4);
  _Float16* Wf     = (_Float16*)carve((size_t)C * C * 2);
  _Float16* Wfh    = (_Float16*)carve((size_t)10 * C * C * 2);
  _Float16* Wfl    = (_Float16*)carve((size_t)10 * C * C * 2);
  _Float16* xh     = (_Float16*)carve((size_t)N * C * 2);
  _Float16* h0     = (_Float16*)carve((size_t)N * C * 2);
  _Float16* h1     = (_Float16*)carve((size_t)N * C * 2);
  _Float16* aggb   = (_Float16*)carve((size_t)N * C * 2);
  _Float16* Pm     = (_Float16*)carve((size_t)N * C * 2);
  _Float16* Qm     = (_Float16*)carve((size_t)N * C * 2);

  hipMemsetAsync(cnt, 0, (size_t)N * 4, stream);
  k_degree<<<(E + 255) / 256, 256, 0, stream>>>(col, cnt, E);
  k_scan<<<1, 1024, 0, stream>>>(cnt, dis, indptr, cursor, N);
  k_csrfill<<<(E + 255) / 256, 256, 0, stream>>>(row, col, dis, cursor,
                                                 emeta, epair, inv, E);
  k_prepwf<<<C * C / 256, 256, 0, stream>>>(fc1_W, Wf);
  k_prepw2<<<10 * C * C / 256, 256, 0, stream>>>(convs_W, fc0_W, Wfh, Wfl);
  k_cvt<<<(N * C / 4 + 255) / 256, 256, 0, stream>>>(x, xh, N * C / 4);

  int aggBlocks  = (N * 64 + 255) / 256;
  int gemmBlocks = (N + 63) / 64;
  const int MSZ = C * C;

  // layer 0 (no skip)
  k_agg<<<aggBlocks, 256, 0, stream>>>(xh, indptr, emeta, dis, aggb, N);
  k_gemm_f16<<<gemmBlocks, 256, 0, stream>>>(aggb, Wfh, Wfl, convs_b,
                                             nullptr, h0, N, 1);
  _Float16* hcur = h0; _Float16* hoth = h1;
  for (int l = 1; l < L; ++l) {
    k_agg<<<aggBlocks, 256, 0, stream>>>(hcur, indptr, emeta, dis, aggb, N);
    k_gemm_f16<<<gemmBlocks, 256, 0, stream>>>(aggb, Wfh + (size_t)l * MSZ,
                                               Wfl + (size_t)l * MSZ,
                                               convs_b + (size_t)l * C, hcur,
                                               hoth, N, 1);
    _Float16* tmp = hcur; hcur = hoth; hoth = tmp;
  }
  // edge MLP: P = h@fc0_W[:128], Q = h@fc0_W[128:] + b0
  k_gemm_f16<<<gemmBlocks, 256, 0, stream>>>(hcur, Wfh + (size_t)8 * MSZ,
                                             Wfl + (size_t)8 * MSZ, nullptr,
                                             nullptr, Pm, N, 0);
  k_gemm_f16<<<gemmBlocks, 256, 0, stream>>>(hcur, Wfh + (size_t)9 * MSZ,
                                             Wfl + (size_t)9 * MSZ, fc0_b,
                                             nullptr, Qm, N, 0);
  k_edge<<<(E + 63) / 64, 256, 0, stream>>>(Pm, Qm, epair, Wf, fc1_b,
                                            fc2_W, fc2_b, tmpout, E);
  k_perm<<<(E + 255) / 256, 256, 0, stream>>>(tmpout, inv, out, E);
}